// Round 16
// baseline (152.823 us; speedup 1.0000x reference)
//
#include <hip/hip_runtime.h>
#include <hip/hip_bf16.h>

// S5 layer, fused MFMA pipeline (runtime segmentation by ws_size):
//   k0  : discretization, lambda power table, FRAGMENT-MAJOR bf16 operands
//   ku  : u fp32 -> bf16 pre-swizzled chunk As-images (for global_load_lds)
//   g1c : persistent CPB=4 Bu GEMM, LDS double-buffered async staging
//         -> BuT packed bf16 + in-register half-chunk finals
//   s2  : cross-half-chunk state chain, 8-batched loads, IN-PLACE (st)
//   g2s : per-chunk (both halves parallel) scan + full-H GEMM + D*u

#define P_ 256
#define H_ 256
#define B_ 16
#define L_ 4096
#define LC 64
#define NC (L_/LC)          // 64 chunks per batch
#define NH (L_/32)          // 128 half-chunks per batch
#define CPB 4               // chunks per persistent g1c block

typedef __attribute__((ext_vector_type(8))) short short8v;
typedef __attribute__((ext_vector_type(4))) float f32x4;

#define GLOBAL_AS __attribute__((address_space(1)))
#define LDS_AS __attribute__((address_space(3)))

static __device__ __forceinline__ void gl_lds16(const void* g, void* l) {
    __builtin_amdgcn_global_load_lds((const GLOBAL_AS unsigned char*)g,
                                     (LDS_AS unsigned char*)l, 16, 0, 0);
}

// hardware v_cvt_pk_bf16_f32 via HIP intrinsic: a -> lo16, b -> hi16 (RNE)
static __device__ __forceinline__ unsigned cvtpk(float a, float b) {
    __hip_bfloat162 h = __float22bfloat162_rn(make_float2(a, b));
    unsigned r;
    __builtin_memcpy(&r, &h, 4);
    return r;
}

static __device__ __forceinline__ unsigned short f2bf(float f) {
    unsigned u = __float_as_uint(f);
    return (unsigned short)((u + 0x7fffu + ((u >> 16) & 1u)) >> 16);
}

// ---------------- k0: discretization + fragment-major operands + powers ----
// Bf: fragment (kt,nt): element row r = nt*16+(l&15), k = kt*32+(l>>4)*8+j
// Cf: fragment (kt,ht): col h = ht*16+(l&15), q = kt*32+(l>>4)*8+j
// lamP [P][16] f32: {l, l4, l8, l12, l16, l32, l48, pad} as (re,im) pairs
__global__ __launch_bounds__(256) void k0_pre(
    const float* __restrict__ Lre, const float* __restrict__ Lim,
    const float* __restrict__ Bre, const float* __restrict__ Bim,
    const float* __restrict__ Cre, const float* __restrict__ Cim,
    const float* __restrict__ lstep,
    float* __restrict__ lam, float* __restrict__ lamP,
    unsigned short* __restrict__ Bf, unsigned short* __restrict__ Cf)
{
    int bx = blockIdx.x;
    int t  = threadIdx.x;
    {
        int p = bx, h = t;
        float laR = Lre[p], laI = Lim[p];
        float st = expf(lstep[p]);
        float er = expf(laR * st);
        float lr = er * cosf(laI * st);
        float li = er * sinf(laI * st);
        float den = laR * laR + laI * laI;
        float nr = lr - 1.0f, ni = li;
        float cr = (nr * laR + ni * laI) / den;
        float ci = (ni * laR - nr * laI) / den;
        float br = Bre[p * H_ + h], bi = Bim[p * H_ + h];
        float vre = cr * br - ci * bi;          // row 2p   (re)
        float vim = cr * bi + ci * br;          // row 2p+1 (im)
        int kt = h >> 5, lsl = ((h >> 3) & 3) << 4, j = h & 7;
        {
            int r = 2 * p;
            int lane = (r & 15) | lsl, nt = r >> 4;
            Bf[(((size_t)kt * 32 + nt) * 64 + lane) * 8 + j] = f2bf(vre);
        }
        {
            int r = 2 * p + 1;
            int lane = (r & 15) | lsl, nt = r >> 4;
            Bf[(((size_t)kt * 32 + nt) * 64 + lane) * 8 + j] = f2bf(vim);
        }
        if (t == 0) {
            lam[2 * p] = lr; lam[2 * p + 1] = li;
            float r2 = lr*lr - li*li,   i2 = 2.f*lr*li;
            float r4 = r2*r2 - i2*i2,   i4 = 2.f*r2*i2;
            float r8 = r4*r4 - i4*i4,   i8 = 2.f*r4*i4;
            float r12 = r8*r4 - i8*i4,  i12 = r8*i4 + i8*r4;
            float r16 = r8*r8 - i8*i8,  i16 = 2.f*r8*i8;
            float r32 = r16*r16 - i16*i16, i32 = 2.f*r16*i16;
            float r48 = r32*r16 - i32*i16, i48 = r32*i16 + i32*r16;
            float* lp = lamP + 16 * p;
            lp[0] = lr;  lp[1] = li;
            lp[2] = r4;  lp[3] = i4;
            lp[4] = r8;  lp[5] = i8;
            lp[6] = r12; lp[7] = i12;
            lp[8] = r16; lp[9] = i16;
            lp[10] = r32; lp[11] = i32;
            lp[12] = r48; lp[13] = i48;
            lp[14] = 0.f; lp[15] = 0.f;
        }
    }
    {
        int h = bx, p = t;
        float vre =  2.0f * Cre[h * P_ + p];    // q = 2p
        float vim = -2.0f * Cim[h * P_ + p];    // q = 2p+1
        int ht = h >> 4;
        #pragma unroll
        for (int e = 0; e < 2; ++e) {
            int q = 2 * p + e;
            int kt = q >> 5, lane = (h & 15) | (((q >> 3) & 3) << 4), j = q & 7;
            Cf[(((size_t)kt * 16 + ht) * 64 + lane) * 8 + j] = f2bf(e ? vim : vre);
        }
    }
}

// ---------------- ku: u fp32 -> bf16 pre-swizzled chunk As-image -----------
// ub[chunk] is 32KB: the exact LDS image g1c's kt-loop expects; granule
// (T, r, g) -> slot s = (g ^ (r&7)) ^ ((T>>1&1)<<2) at T*8192 + r*128 + s*16.
__global__ __launch_bounds__(256) void ku_pre(
    const float* __restrict__ us, unsigned short* __restrict__ ub)
{
    int chunk = blockIdx.x;
    int t = threadIdx.x;
    const float* src = us + (size_t)chunk * 16384;
    unsigned short* dst = ub + (size_t)chunk * 16384;
    #pragma unroll
    for (int i = 0; i < 8; ++i) {
        int gid = i * 256 + t;                 // 0..2047 granules
        int T = gid >> 9, rem = gid & 511, r = rem >> 3, g = rem & 7;
        int s = (g ^ (r & 7)) ^ (((T >> 1) & 1) << 2);
        const float4* sp = (const float4*)(src + (size_t)r * 256 + T * 64 + g * 8);
        float4 v0 = sp[0], v1 = sp[1];
        uint4 o;
        o.x = cvtpk(v0.x, v0.y); o.y = cvtpk(v0.z, v0.w);
        o.z = cvtpk(v1.x, v1.y); o.w = cvtpk(v1.z, v1.w);
        *(uint4*)(dst + (size_t)T * 4096 + r * 64 + s * 8) = o;
    }
}

// ---------------- g1c: persistent CPB-chunk Bu GEMM, async dbuf staging ----
// block = 64 u-rows x 256 N-cols (by-split); 8 waves, wave w: 32 cols.
__global__ __launch_bounds__(512, 4) void g1c_gemm(
    const unsigned short* __restrict__ ub,
    const unsigned short* __restrict__ Bf,
    const float* __restrict__ lamP,
    unsigned* __restrict__ BuT, float2* __restrict__ st)
{
    __shared__ __align__(16) char As[2][32768];
    int tid = threadIdx.x, w = tid >> 6, lane = tid & 63;
    int ci0 = blockIdx.x * CPB;
    int by = blockIdx.y;
    int lr_ = lane & 15, lk = lane >> 4, r7 = lr_ & 7;
    const unsigned short* bf0 = Bf + (((size_t)(by * 16 + w * 2 + 0)) * 64 + lane) * 8;
    const unsigned short* bf1 = Bf + (((size_t)(by * 16 + w * 2 + 1)) * 64 + lane) * 8;
    bool evenl = (lr_ & 1) == 0;
    int mA = evenl ? 0 : 2;

    // prologue: async-stage chunk ci0 -> buf 0 (linear copy, pre-swizzled src)
    {
        const char* src = (const char*)(ub + (size_t)ci0 * 16384);
        #pragma unroll
        for (int j = 0; j < 4; ++j) {
            int off = (j * 8 + w) * 1024;
            gl_lds16(src + off + lane * 16, &As[0][off]);
        }
    }
    __syncthreads();                            // buf0 ready

    int cur = 0;
    for (int it = 0; it < CPB; ++it) {
        int ci = ci0 + it;
        // issue next chunk's staging NOW; in flight under this chunk's compute
        if (it + 1 < CPB) {
            const char* src = (const char*)(ub + (size_t)(ci + 1) * 16384);
            #pragma unroll
            for (int j = 0; j < 4; ++j) {
                int off = (j * 8 + w) * 1024;
                gl_lds16(src + off + lane * 16, &As[cur ^ 1][off]);
            }
        }

        f32x4 acc[4][2];
        #pragma unroll
        for (int m = 0; m < 4; ++m)
            #pragma unroll
            for (int n = 0; n < 2; ++n)
                acc[m][n] = (f32x4){0.f, 0.f, 0.f, 0.f};

        #pragma unroll
        for (int kt = 0; kt < 8; ++kt) {
            short8v b0 = *(const short8v*)(bf0 + (size_t)kt * 16384);
            short8v b1 = *(const short8v*)(bf1 + (size_t)kt * 16384);
            int T = kt >> 1;
            int q2 = (((kt & 1) * 4 + lk) ^ r7) ^ (((kt >> 2) & 1) << 2);
            short8v a_[4];
            #pragma unroll
            for (int m = 0; m < 4; ++m)
                a_[m] = *(const short8v*)(&As[cur][T * 8192 + (m * 16 + lr_) * 128 + (q2 << 4)]);
            #pragma unroll
            for (int m = 0; m < 4; ++m)
                acc[m][0] = __builtin_amdgcn_mfma_f32_16x16x32_bf16(a_[m], b0, acc[m][0], 0, 0, 0);
            #pragma unroll
            for (int m = 0; m < 4; ++m)
                acc[m][1] = __builtin_amdgcn_mfma_f32_16x16x32_bf16(a_[m], b1, acc[m][1], 0, 0, 0);
        }

        // epilogue: pack-then-shfl merge, write BuT, in-reg half-chunk finals
        size_t cb = (size_t)ci * 16384;
        #pragma unroll
        for (int n = 0; n < 2; ++n) {
            int p = by * 128 + w * 16 + n * 8 + (lr_ >> 1);
            unsigned dw[4][4];
            #pragma unroll
            for (int m = 0; m < 4; ++m) {
                unsigned myA = cvtpk(acc[m][n][0], acc[m][n][1]);
                unsigned myB = cvtpk(acc[m][n][2], acc[m][n][3]);
                unsigned pA = __shfl_xor(myA, 1);
                unsigned pB = __shfl_xor(myB, 1);
                if (evenl) {
                    dw[m][0] = (myA & 0xffffu) | (pA << 16);
                    dw[m][1] = (myA >> 16) | (pA & 0xffff0000u);
                    dw[m][2] = (myB & 0xffffu) | (pB << 16);
                    dw[m][3] = (myB >> 16) | (pB & 0xffff0000u);
                } else {
                    dw[m][0] = (pA & 0xffffu) | (myA << 16);
                    dw[m][1] = (pA >> 16) | (myA & 0xffff0000u);
                    dw[m][2] = (pB & 0xffffu) | (myB << 16);
                    dw[m][3] = (pB >> 16) | (myB & 0xffff0000u);
                }
            }
            #pragma unroll
            for (int t2 = 0; t2 < 2; ++t2) {
                int m = mA + t2;
                uint4 vv = make_uint4(dw[m][0], dw[m][1], dw[m][2], dw[m][3]);
                *(uint4*)&BuT[cb + (size_t)p * 64 + m * 16 + lk * 4] = vv;
            }
            // half-chunk finals from bf16-rounded values (consistent with g2s)
            const float4* lp = (const float4*)(lamP + 16 * p);
            float4 P0 = lp[0];   // l, l4
            float4 P1 = lp[1];   // l8, l12
            float4 P2 = lp[2];   // l16, l32
            float Lr = P0.x, Li = P0.y;
            float Fr[4], Fi[4];
            #pragma unroll
            for (int m = 0; m < 4; ++m) {
                float fr = 0.f, fi = 0.f;
                #pragma unroll
                for (int i = 0; i < 4; ++i) {
                    float ur = __uint_as_float(dw[m][i] << 16);
                    float ui = __uint_as_float(dw[m][i] & 0xffff0000u);
                    float nr2 = Lr * fr - Li * fi + ur;
                    float ni2 = Lr * fi + Li * fr + ui;
                    fr = nr2; fi = ni2;
                }
                Fr[m] = fr; Fi[m] = fi;
            }
            float H0r = P2.x*Fr[0] - P2.y*Fi[0] + Fr[1];
            float H0i = P2.x*Fi[0] + P2.y*Fr[0] + Fi[1];
            float H1r = P2.x*Fr[2] - P2.y*Fi[2] + Fr[3];
            float H1i = P2.x*Fi[2] + P2.y*Fr[2] + Fi[3];
            float gr = (lk == 3) ? 1.f : (lk == 2) ? P0.z : (lk == 1) ? P1.x : P1.z;
            float gi = (lk == 3) ? 0.f : (lk == 2) ? P0.w : (lk == 1) ? P1.y : P1.w;
            float G0r = gr * H0r - gi * H0i, G0i = gr * H0i + gi * H0r;
            float G1r = gr * H1r - gi * H1i, G1i = gr * H1i + gi * H1r;
            G0r += __shfl_xor(G0r, 16); G0i += __shfl_xor(G0i, 16);
            G1r += __shfl_xor(G1r, 16); G1i += __shfl_xor(G1i, 16);
            G0r += __shfl_xor(G0r, 32); G0i += __shfl_xor(G0i, 32);
            G1r += __shfl_xor(G1r, 32); G1i += __shfl_xor(G1i, 32);
            if (evenl && lk == 0) {
                st[((size_t)ci * 2 + 0) * P_ + p] = make_float2(G0r, G0i);
                st[((size_t)ci * 2 + 1) * P_ + p] = make_float2(G1r, G1i);
            }
        }
        __syncthreads();      // drains prefetch (mostly done) + guards buffers
        cur ^= 1;
    }
}

// ---------------- s2: cross-half-chunk chain, batched loads, in-place ------
__global__ __launch_bounds__(256) void s2_chain(
    const float* __restrict__ lamP, float2* __restrict__ st)
{
    int bl = blockIdx.x;
    int p = threadIdx.x;
    float ar = lamP[16 * p + 10], ai = lamP[16 * p + 11];   // lambda^32
    float sr = 0.f, si = 0.f;
    float2* bp = st + (size_t)bl * NH * P_ + p;
    float2 f[8], fn[8];
    #pragma unroll
    for (int j = 0; j < 8; ++j) f[j] = bp[(size_t)j * P_];
    for (int c0 = 0; c0 < NH; c0 += 8) {
        if (c0 + 8 < NH) {
            #pragma unroll
            for (int j = 0; j < 8; ++j) fn[j] = bp[(size_t)(c0 + 8 + j) * P_];
        }
        #pragma unroll
        for (int j = 0; j < 8; ++j) {
            float2 t = f[j];
            bp[(size_t)(c0 + j) * P_] = make_float2(sr, si);
            float nr = ar * sr - ai * si + t.x;
            float ni = ar * si + ai * sr + t.y;
            sr = nr; si = ni;
        }
        #pragma unroll
        for (int j = 0; j < 8; ++j) f[j] = fn[j];
    }
}

// ---------------- g2s: per-chunk scan (both halves) + full-H GEMM + D*u ----
// block = 64 rows x H=256; 512 thr; 64KB LDS -> 2 blocks/CU.
__global__ __launch_bounds__(512, 4) void g2s_gemm(
    const unsigned* __restrict__ BuT,
    const unsigned short* __restrict__ Cf,
    const float* __restrict__ lam, const float2* __restrict__ st,
    const float* __restrict__ useg, const float* __restrict__ Dv,
    float* __restrict__ yseg)
{
    __shared__ __align__(16) char xs[65536];   // [2 halves][8 T][32 rows][128B]
    int tid = threadIdx.x, w = tid >> 6, lane = tid & 63;
    int ci = blockIdx.x;                       // chunk index (segment-local)

    // phase 1: both half-chunks scanned in parallel (512 threads = 2 x 256 p)
    {
        int p = tid & 255, half = tid >> 8;
        float lr = lam[2 * p], li = lam[2 * p + 1];
        float2 s0 = st[((size_t)ci * 2 + half) * P_ + p];
        const uint4* bp = (const uint4*)(BuT + (size_t)ci * 16384 + (size_t)p * 64 + half * 32);
        uint4 dq[8];
        #pragma unroll
        for (int t = 0; t < 8; ++t) dq[t] = bp[t];
        float xr = s0.x, xi = s0.y;
        int T = p >> 5, qd = (p & 31) >> 2, pos = p & 3;
        char* base = xs + half * 32768 + T * 4096 + (pos << 2);
        #pragma unroll
        for (int t = 0; t < 8; ++t) {
            unsigned wv4[4] = {dq[t].x, dq[t].y, dq[t].z, dq[t].w};
            #pragma unroll
            for (int e = 0; e < 4; ++e) {
                int j = t * 4 + e;
                unsigned wv = wv4[e];
                float ur = __uint_as_float(wv << 16);
                float ui = __uint_as_float(wv & 0xffff0000u);
                float nr = lr * xr - li * xi + ur;
                float ni = lr * xi + li * xr + ui;
                xr = nr; xi = ni;
                *(unsigned*)(base + j * 128 + ((qd ^ (j & 7)) << 4)) = cvtpk(xr, xi);
            }
        }
    }

    // phase 2: GEMM  y[64][256] = x[64][512] * Cf^T
    int lr_ = lane & 15, lk = lane >> 4, r7 = lr_ & 7;
    int h0 = w * 32;                           // 8 waves x 32 h-cols
    const unsigned short* cf0 = Cf + (((size_t)(w * 2 + 0)) * 64 + lane) * 8;
    const unsigned short* cf1 = Cf + (((size_t)(w * 2 + 1)) * 64 + lane) * 8;

    f32x4 acc[4][2];
    #pragma unroll
    for (int m = 0; m < 4; ++m)
        #pragma unroll
        for (int n = 0; n < 2; ++n)
            acc[m][n] = (f32x4){0.f, 0.f, 0.f, 0.f};

    __syncthreads();

    #pragma unroll
    for (int kt = 0; kt < 16; ++kt) {
        short8v b0 = *(const short8v*)(cf0 + (size_t)kt * 8192);
        short8v b1 = *(const short8v*)(cf1 + (size_t)kt * 8192);
        int T = kt >> 1, q2 = (kt & 1) * 4 + lk;
        short8v a_[4];
        #pragma unroll
        for (int m = 0; m < 4; ++m)
            a_[m] = *(const short8v*)(xs + (m >> 1) * 32768 + T * 4096
                                      + ((m & 1) * 16 + lr_) * 128 + ((q2 ^ r7) << 4));
        #pragma unroll
        for (int m = 0; m < 4; ++m)
            acc[m][0] = __builtin_amdgcn_mfma_f32_16x16x32_bf16(a_[m], b0, acc[m][0], 0, 0, 0);
        #pragma unroll
        for (int m = 0; m < 4; ++m)
            acc[m][1] = __builtin_amdgcn_mfma_f32_16x16x32_bf16(a_[m], b1, acc[m][1], 0, 0, 0);
    }

    float d_[2];
    #pragma unroll
    for (int n = 0; n < 2; ++n) d_[n] = Dv[h0 + n * 16 + lr_];
    #pragma unroll
    for (int m = 0; m < 4; ++m)
        #pragma unroll
        for (int n = 0; n < 2; ++n)
            #pragma unroll
            for (int i = 0; i < 4; ++i) {
                int rl = m * 16 + lk * 4 + i;
                int col = h0 + n * 16 + lr_;
                size_t off = ((size_t)ci * 64 + rl) * 256 + col;
                yseg[off] = acc[m][n][i] + d_[n] * useg[off];
            }
}

// ---------------- launch ----------------
extern "C" void kernel_launch(void* const* d_in, const int* in_sizes, int n_in,
                              void* d_out, int out_size, void* d_ws, size_t ws_size,
                              hipStream_t stream) {
    (void)in_sizes; (void)n_in; (void)out_size;
    const float* u    = (const float*)d_in[0];
    const float* Lre  = (const float*)d_in[1];
    const float* Lim  = (const float*)d_in[2];
    const float* Bre  = (const float*)d_in[3];
    const float* Bim  = (const float*)d_in[4];
    const float* Cre  = (const float*)d_in[5];
    const float* Cim  = (const float*)d_in[6];
    const float* Dv   = (const float*)d_in[7];
    const float* lstep= (const float*)d_in[8];

    // pick largest segment size the workspace allows
    const size_t fixed = 2048 + (size_t)16 * P_ * 4
                       + (size_t)512 * 256 * 2 + (size_t)256 * 512 * 2;
    // per batch: BuT (4MB) + ub (2MB) + st (256KB)
    const size_t perb = (size_t)L_ * 256 * 4 + (size_t)L_ * 256 * 2 + (size_t)NH * P_ * 8;
    int nb = 4;
    if (ws_size >= fixed + 16 * perb + 4096) nb = 16;
    else if (ws_size >= fixed + 8 * perb + 4096) nb = 8;
    int nseg = B_ / nb;

    char* w0 = (char*)d_ws;
    float* lam   = (float*)w0;  w0 += 2048;
    float* lamP  = (float*)w0;  w0 += (size_t)16 * P_ * 4;
    unsigned short* Bf = (unsigned short*)w0; w0 += (size_t)512 * 256 * 2;
    unsigned short* Cf = (unsigned short*)w0; w0 += (size_t)256 * 512 * 2;
    float2* st = (float2*)w0;   w0 += (size_t)nb * NH * P_ * 8;
    unsigned short* ub = (unsigned short*)w0; w0 += (size_t)nb * L_ * 256 * 2;
    unsigned* BuT = (unsigned*)w0;

    k0_pre<<<256, 256, 0, stream>>>(Lre, Lim, Bre, Bim, Cre, Cim, lstep,
                                    lam, lamP, Bf, Cf);
    for (int s = 0; s < nseg; ++s) {
        const float* us = u + (size_t)s * nb * L_ * H_;
        float* ys = (float*)d_out + (size_t)s * nb * L_ * H_;
        ku_pre<<<nb * NC, 256, 0, stream>>>(us, ub);
        g1c_gemm<<<dim3(nb * NC / CPB, 2), 512, 0, stream>>>(ub, Bf, lamP, BuT, st);
        s2_chain<<<nb, 256, 0, stream>>>(lamP, st);
        g2s_gemm<<<nb * NC, 512, 0, stream>>>(BuT, Cf, lam, st, us, Dv, ys);
    }
}

// Round 18
// 111.301 us; speedup vs baseline: 1.3731x; 1.3731x over previous
//
#include <hip/hip_runtime.h>
#include <hip/hip_bf16.h>
#include <hip/hip_cooperative_groups.h>

namespace cg = cooperative_groups;

// S5 layer. Preferred: single fused cooperative kernel (Bu never leaves LDS).
// Fallback (occupancy guard fails): R12 3-kernel pipeline.
//   k0    : discretization, lambda powers, fragment-major bf16 operands
//   fused : P1 Bu GEMM -> Bu in LDS (64KB, As overlaid) + half finals -> st;
//           grid.sync; P2 chain; grid.sync; P3 in-place LDS scan + out GEMM.
//   g1c/s2/g2s : fallback pipeline (BuT through HBM).

#define P_ 256
#define H_ 256
#define B_ 16
#define L_ 4096
#define NC 64               // chunks per batch (64 rows each)
#define NH 128              // half-chunks per batch

typedef __attribute__((ext_vector_type(8))) short short8v;
typedef __attribute__((ext_vector_type(4))) float f32x4;

static __device__ __forceinline__ unsigned cvtpk(float a, float b) {
    __hip_bfloat162 h = __float22bfloat162_rn(make_float2(a, b));
    unsigned r;
    __builtin_memcpy(&r, &h, 4);
    return r;
}

static __device__ __forceinline__ unsigned short f2bf(float f) {
    unsigned u = __float_as_uint(f);
    return (unsigned short)((u + 0x7fffu + ((u >> 16) & 1u)) >> 16);
}

// ---------------- k0: discretization + fragment-major operands + powers ----
__global__ __launch_bounds__(256) void k0_pre(
    const float* __restrict__ Lre, const float* __restrict__ Lim,
    const float* __restrict__ Bre, const float* __restrict__ Bim,
    const float* __restrict__ Cre, const float* __restrict__ Cim,
    const float* __restrict__ lstep,
    float* __restrict__ lam, float* __restrict__ lamP,
    unsigned short* __restrict__ Bf, unsigned short* __restrict__ Cf)
{
    int bx = blockIdx.x;
    int t  = threadIdx.x;
    {
        int p = bx, h = t;
        float laR = Lre[p], laI = Lim[p];
        float st = expf(lstep[p]);
        float er = expf(laR * st);
        float lr = er * cosf(laI * st);
        float li = er * sinf(laI * st);
        float den = laR * laR + laI * laI;
        float nr = lr - 1.0f, ni = li;
        float cr = (nr * laR + ni * laI) / den;
        float ci = (ni * laR - nr * laI) / den;
        float br = Bre[p * H_ + h], bi = Bim[p * H_ + h];
        float vre = cr * br - ci * bi;          // row 2p   (re)
        float vim = cr * bi + ci * br;          // row 2p+1 (im)
        int kt = h >> 5, lsl = ((h >> 3) & 3) << 4, j = h & 7;
        {
            int r = 2 * p;
            int lane = (r & 15) | lsl, nt = r >> 4;
            Bf[(((size_t)kt * 32 + nt) * 64 + lane) * 8 + j] = f2bf(vre);
        }
        {
            int r = 2 * p + 1;
            int lane = (r & 15) | lsl, nt = r >> 4;
            Bf[(((size_t)kt * 32 + nt) * 64 + lane) * 8 + j] = f2bf(vim);
        }
        if (t == 0) {
            lam[2 * p] = lr; lam[2 * p + 1] = li;
            float r2 = lr*lr - li*li,   i2 = 2.f*lr*li;
            float r4 = r2*r2 - i2*i2,   i4 = 2.f*r2*i2;
            float r8 = r4*r4 - i4*i4,   i8 = 2.f*r4*i4;
            float r12 = r8*r4 - i8*i4,  i12 = r8*i4 + i8*r4;
            float r16 = r8*r8 - i8*i8,  i16 = 2.f*r8*i8;
            float r32 = r16*r16 - i16*i16, i32 = 2.f*r16*i16;
            float r48 = r32*r16 - i32*i16, i48 = r32*i16 + i32*r16;
            float* lp = lamP + 16 * p;
            lp[0] = lr;  lp[1] = li;
            lp[2] = r4;  lp[3] = i4;
            lp[4] = r8;  lp[5] = i8;
            lp[6] = r12; lp[7] = i12;
            lp[8] = r16; lp[9] = i16;
            lp[10] = r32; lp[11] = i32;
            lp[12] = r48; lp[13] = i48;
            lp[14] = 0.f; lp[15] = 0.f;
        }
    }
    {
        int h = bx, p = t;
        float vre =  2.0f * Cre[h * P_ + p];    // q = 2p
        float vim = -2.0f * Cim[h * P_ + p];    // q = 2p+1
        int ht = h >> 4;
        #pragma unroll
        for (int e = 0; e < 2; ++e) {
            int q = 2 * p + e;
            int kt = q >> 5, lane = (h & 15) | (((q >> 3) & 3) << 4), j = q & 7;
            Cf[(((size_t)kt * 16 + ht) * 64 + lane) * 8 + j] = f2bf(e ? vim : vre);
        }
    }
}

// ---------------- fused: 64KB LDS (As overlays Bu1 slot) -------------------
// grid 512 = 8 batches x 64 chunks; 512 thr; 2 blocks/CU.
__global__ __launch_bounds__(512, 4) void fused_s5(
    const float* __restrict__ u,
    const unsigned short* __restrict__ Bf,
    const unsigned short* __restrict__ Cf,
    const float* __restrict__ lam, const float* __restrict__ lamP,
    float2* __restrict__ stbuf, const float* __restrict__ Dv,
    float* __restrict__ y)
{
    __shared__ __align__(16) char lds[65536];   // Bu0 [0,32K) | Bu1 [32K,64K)
    char* As = lds + 32768;                     // overlays Bu1's first 16KB
    cg::grid_group grid = cg::this_grid();
    int tid = threadIdx.x, w = tid >> 6, lane = tid & 63;
    int b = blockIdx.x, bl = b >> 6, c = b & 63;
    int lr_ = lane & 15, lk = lane >> 4, r7 = lr_ & 7;
    bool evenl = (lr_ & 1) == 0;

    for (int s = 0; s < 2; ++s) {
        int bt = s * 8 + bl;
        float2* st = stbuf + (size_t)s * 8 * NH * P_;
        const float* uc = u + ((size_t)bt * L_ + c * 64) * 256;

        // ---------- phase 1: per-half Bu GEMM -> Bu LDS + finals -> st ------
        for (int h = 0; h < 2; ++h) {
            char* Bu = lds + h * 32768;
            {
                const float4* ub = (const float4*)(uc + h * 32 * 256);
                #pragma unroll
                for (int i = 0; i < 4; ++i) {
                    int f = i * 512 + tid;             // 0..2047
                    int r = f >> 6, c4 = f & 63;
                    float4 v = ub[f];
                    uint2 o;
                    o.x = cvtpk(v.x, v.y);
                    o.y = cvtpk(v.z, v.w);
                    int pos = (((c4 >> 1) & 7) ^ (r & 7)) ^ (((c4 >> 5) & 1) << 2);
                    *(uint2*)(As + (c4 >> 4) * 4096 + r * 128 + (pos << 4) + (c4 & 1) * 8) = o;
                }
            }
            __syncthreads();

            f32x4 acc[2][4];
            #pragma unroll
            for (int m = 0; m < 2; ++m)
                #pragma unroll
                for (int n = 0; n < 4; ++n)
                    acc[m][n] = (f32x4){0.f, 0.f, 0.f, 0.f};

            #pragma unroll
            for (int kt = 0; kt < 8; ++kt) {
                short8v b_[4];
                #pragma unroll
                for (int n = 0; n < 4; ++n)
                    b_[n] = *(const short8v*)(Bf + (((size_t)kt * 32 + w * 4 + n) * 64 + lane) * 8);
                int T = kt >> 1;
                int q2 = (((kt & 1) * 4 + lk) ^ r7) ^ (((kt >> 2) & 1) << 2);
                short8v a_[2];
                #pragma unroll
                for (int m = 0; m < 2; ++m)
                    a_[m] = *(const short8v*)(As + T * 4096 + (m * 16 + lr_) * 128 + (q2 << 4));
                #pragma unroll
                for (int n = 0; n < 4; ++n)
                    #pragma unroll
                    for (int m = 0; m < 2; ++m)
                        acc[m][n] = __builtin_amdgcn_mfma_f32_16x16x32_bf16(a_[m], b_[n], acc[m][n], 0, 0, 0);
            }
            if (h == 1) __syncthreads();   // all As reads done before overwrite

            // epilogue: pair re/im, write Bu LDS (xs-pattern), finals -> st
            int mw = evenl ? 0 : 1;
            #pragma unroll
            for (int n = 0; n < 4; ++n) {
                int p = w * 32 + n * 8 + (lr_ >> 1);
                unsigned dw[2][4];
                #pragma unroll
                for (int m = 0; m < 2; ++m) {
                    unsigned myA = cvtpk(acc[m][n][0], acc[m][n][1]);
                    unsigned myB = cvtpk(acc[m][n][2], acc[m][n][3]);
                    unsigned pA = __shfl_xor(myA, 1);
                    unsigned pB = __shfl_xor(myB, 1);
                    if (evenl) {
                        dw[m][0] = (myA & 0xffffu) | (pA << 16);
                        dw[m][1] = (myA >> 16) | (pA & 0xffff0000u);
                        dw[m][2] = (myB & 0xffffu) | (pB << 16);
                        dw[m][3] = (myB >> 16) | (pB & 0xffff0000u);
                    } else {
                        dw[m][0] = (pA & 0xffffu) | (myA << 16);
                        dw[m][1] = (pA >> 16) | (myA & 0xffff0000u);
                        dw[m][2] = (pB & 0xffffu) | (myB << 16);
                        dw[m][3] = (pB >> 16) | (myB & 0xffff0000u);
                    }
                }
                int T = p >> 5, qd = (p & 31) >> 2, pos4 = (p & 3) * 4;
                #pragma unroll
                for (int i = 0; i < 4; ++i) {
                    int j = mw * 16 + lk * 4 + i;
                    *(unsigned*)(Bu + T * 4096 + j * 128 + ((qd ^ (j & 7)) << 4) + pos4) = dw[mw][i];
                }
                // half-chunk final from bf16-rounded dw
                const float4* lp = (const float4*)(lamP + 16 * p);
                float4 P0 = lp[0];   // l, l4
                float4 P1 = lp[1];   // l8, l12
                float4 P2 = lp[2];   // l16, l32
                float Lr = P0.x, Li = P0.y;
                float Fr[2], Fi[2];
                #pragma unroll
                for (int m = 0; m < 2; ++m) {
                    float fr = 0.f, fi = 0.f;
                    #pragma unroll
                    for (int i = 0; i < 4; ++i) {
                        float ur = __uint_as_float(dw[m][i] << 16);
                        float ui = __uint_as_float(dw[m][i] & 0xffff0000u);
                        float nr2 = Lr * fr - Li * fi + ur;
                        float ni2 = Lr * fi + Li * fr + ui;
                        fr = nr2; fi = ni2;
                    }
                    Fr[m] = fr; Fi[m] = fi;
                }
                float Hr = P2.x * Fr[0] - P2.y * Fi[0] + Fr[1];
                float Hi = P2.x * Fi[0] + P2.y * Fr[0] + Fi[1];
                float gr = (lk == 3) ? 1.f : (lk == 2) ? P0.z : (lk == 1) ? P1.x : P1.z;
                float gi = (lk == 3) ? 0.f : (lk == 2) ? P0.w : (lk == 1) ? P1.y : P1.w;
                float Gr = gr * Hr - gi * Hi;
                float Gi = gr * Hi + gi * Hr;
                Gr += __shfl_xor(Gr, 16); Gi += __shfl_xor(Gi, 16);
                Gr += __shfl_xor(Gr, 32); Gi += __shfl_xor(Gi, 32);
                if (evenl && lk == 0)
                    st[((size_t)(bl * NC + c) * 2 + h) * P_ + p] = make_float2(Gr, Gi);
            }
            __syncthreads();
        }

        __threadfence();
        grid.sync();

        // ---------- phase 2: chain per batch (blocks 0..7) -----------------
        if (b < 8 && tid < 256) {
            int p = tid;
            float ar = lamP[16 * p + 10], ai = lamP[16 * p + 11];   // l^32
            float sr = 0.f, si = 0.f;
            float2* bp = st + (size_t)b * NH * P_ + p;
            float2 f[8], fn[8];
            #pragma unroll
            for (int j = 0; j < 8; ++j) f[j] = bp[(size_t)j * P_];
            for (int c0 = 0; c0 < NH; c0 += 8) {
                if (c0 + 8 < NH) {
                    #pragma unroll
                    for (int j = 0; j < 8; ++j) fn[j] = bp[(size_t)(c0 + 8 + j) * P_];
                }
                #pragma unroll
                for (int j = 0; j < 8; ++j) {
                    float2 t = f[j];
                    bp[(size_t)(c0 + j) * P_] = make_float2(sr, si);
                    float nr = ar * sr - ai * si + t.x;
                    float ni = ar * si + ai * sr + t.y;
                    sr = nr; si = ni;
                }
                #pragma unroll
                for (int j = 0; j < 8; ++j) f[j] = fn[j];
            }
        }
        __threadfence();
        grid.sync();

        // ---------- phase 3: in-place LDS scan + output GEMM + D*u ---------
        {
            int h = tid >> 8, p = tid & 255;
            char* Bu = lds + h * 32768;
            float lr = lam[2 * p], li = lam[2 * p + 1];
            float2 s0 = st[((size_t)(bl * NC + c) * 2 + h) * P_ + p];
            float xr = s0.x, xi = s0.y;
            int T = p >> 5, qd = (p & 31) >> 2, pos4 = (p & 3) * 4;
            #pragma unroll 8
            for (int j = 0; j < 32; ++j) {
                unsigned* ap = (unsigned*)(Bu + T * 4096 + j * 128 + ((qd ^ (j & 7)) << 4) + pos4);
                unsigned wv = *ap;
                float ur = __uint_as_float(wv << 16);
                float ui = __uint_as_float(wv & 0xffff0000u);
                float nr = lr * xr - li * xi + ur;
                float ni = lr * xi + li * xr + ui;
                xr = nr; xi = ni;
                *ap = cvtpk(xr, xi);
            }
        }
        __syncthreads();
        {
            f32x4 acc2[4][2];
            #pragma unroll
            for (int m = 0; m < 4; ++m)
                #pragma unroll
                for (int n = 0; n < 2; ++n)
                    acc2[m][n] = (f32x4){0.f, 0.f, 0.f, 0.f};

            #pragma unroll
            for (int kt = 0; kt < 16; ++kt) {
                short8v b_[2];
                #pragma unroll
                for (int n = 0; n < 2; ++n)
                    b_[n] = *(const short8v*)(Cf + (((size_t)kt * 16 + w * 2 + n) * 64 + lane) * 8);
                int T = kt >> 1, q2 = (kt & 1) * 4 + lk;
                short8v a_[4];
                #pragma unroll
                for (int m = 0; m < 4; ++m)
                    a_[m] = *(const short8v*)(lds + (m >> 1) * 32768 + T * 4096
                                              + ((m & 1) * 16 + lr_) * 128 + ((q2 ^ r7) << 4));
                #pragma unroll
                for (int m = 0; m < 4; ++m)
                    acc2[m][0] = __builtin_amdgcn_mfma_f32_16x16x32_bf16(a_[m], b_[0], acc2[m][0], 0, 0, 0);
                #pragma unroll
                for (int m = 0; m < 4; ++m)
                    acc2[m][1] = __builtin_amdgcn_mfma_f32_16x16x32_bf16(a_[m], b_[1], acc2[m][1], 0, 0, 0);
            }

            float d_[2];
            #pragma unroll
            for (int n = 0; n < 2; ++n) d_[n] = Dv[w * 32 + n * 16 + lr_];
            float* yc = y + ((size_t)bt * L_ + c * 64) * 256;
            #pragma unroll
            for (int m = 0; m < 4; ++m)
                #pragma unroll
                for (int n = 0; n < 2; ++n)
                    #pragma unroll
                    for (int i = 0; i < 4; ++i) {
                        int row = m * 16 + lk * 4 + i;
                        int col = w * 32 + n * 16 + lr_;
                        size_t off = (size_t)row * 256 + col;
                        yc[off] = acc2[m][n][i] + d_[n] * uc[off];
                    }
        }
        __syncthreads();   // LDS safe before next segment's phase 1
    }
}

// ================= fallback pipeline (R12, proven 111.7 us) ================
__global__ __launch_bounds__(512, 4) void g1c_gemm(
    const float* __restrict__ us,
    const unsigned short* __restrict__ Bf,
    const float* __restrict__ lamP,
    unsigned* __restrict__ BuT, float2* __restrict__ st)
{
    __shared__ __align__(16) char As[32768];
    int tid = threadIdx.x, w = tid >> 6, lane = tid & 63;
    int ci = blockIdx.x;
    int by = blockIdx.y;

    {
        const float4* ub = (const float4*)(us + (size_t)ci * 16384);
        #pragma unroll
        for (int jj = 0; jj < 8; ++jj) {
            int f = jj * 512 + tid;
            int r = f >> 6, c4 = f & 63;
            float4 v = ub[f];
            uint2 o;
            o.x = cvtpk(v.x, v.y);
            o.y = cvtpk(v.z, v.w);
            int pos = (((c4 >> 1) & 7) ^ (r & 7)) ^ (((c4 >> 5) & 1) << 2);
            *(uint2*)(As + (c4 >> 4) * 8192 + r * 128 + (pos << 4) + (c4 & 1) * 8) = o;
        }
    }

    int lr_ = lane & 15, lk = lane >> 4, r7 = lr_ & 7;
    const unsigned short* bf0 = Bf + (((size_t)(by * 16 + w * 2 + 0)) * 64 + lane) * 8;
    const unsigned short* bf1 = Bf + (((size_t)(by * 16 + w * 2 + 1)) * 64 + lane) * 8;
    bool evenl = (lr_ & 1) == 0;
    int mA = evenl ? 0 : 2;

    f32x4 acc[4][2];
    #pragma unroll
    for (int m = 0; m < 4; ++m)
        #pragma unroll
        for (int n = 0; n < 2; ++n)
            acc[m][n] = (f32x4){0.f, 0.f, 0.f, 0.f};

    short8v bcur[2], bnxt[2];
    bcur[0] = *(const short8v*)bf0;
    bcur[1] = *(const short8v*)bf1;
    __syncthreads();

    #pragma unroll
    for (int kt = 0; kt < 8; ++kt) {
        if (kt < 7) {
            bnxt[0] = *(const short8v*)(bf0 + (size_t)(kt + 1) * 16384);
            bnxt[1] = *(const short8v*)(bf1 + (size_t)(kt + 1) * 16384);
        }
        int T = kt >> 1;
        int q2 = (((kt & 1) * 4 + lk) ^ r7) ^ (((kt >> 2) & 1) << 2);
        short8v a_[4];
        #pragma unroll
        for (int m = 0; m < 4; ++m)
            a_[m] = *(const short8v*)(As + T * 8192 + (m * 16 + lr_) * 128 + (q2 << 4));
        #pragma unroll
        for (int n = 0; n < 2; ++n)
            #pragma unroll
            for (int m = 0; m < 4; ++m)
                acc[m][n] = __builtin_amdgcn_mfma_f32_16x16x32_bf16(a_[m], bcur[n], acc[m][n], 0, 0, 0);
        bcur[0] = bnxt[0]; bcur[1] = bnxt[1];
    }

    size_t cb = (size_t)ci * 16384;
    #pragma unroll
    for (int n = 0; n < 2; ++n) {
        int p = by * 128 + w * 16 + n * 8 + (lr_ >> 1);
        unsigned dw[4][4];
        #pragma unroll
        for (int m = 0; m < 4; ++m) {
            unsigned myA = cvtpk(acc[m][n][0], acc[m][n][1]);
            unsigned myB = cvtpk(acc[m][n][2], acc[m][n][3]);
            unsigned pA = __shfl_xor(myA, 1);
            unsigned pB = __shfl_xor(myB, 1);
            if (evenl) {
                dw[m][0] = (myA & 0xffffu) | (pA << 16);
                dw[m][1] = (myA >> 16) | (pA & 0xffff0000u);
                dw[m][2] = (myB & 0xffffu) | (pB << 16);
                dw[m][3] = (myB >> 16) | (pB & 0xffff0000u);
            } else {
                dw[m][0] = (pA & 0xffffu) | (myA << 16);
                dw[m][1] = (pA >> 16) | (myA & 0xffff0000u);
                dw[m][2] = (pB & 0xffffu) | (myB << 16);
                dw[m][3] = (pB >> 16) | (myB & 0xffff0000u);
            }
        }
        #pragma unroll
        for (int t2 = 0; t2 < 2; ++t2) {
            int m = mA + t2;
            uint4 vv = make_uint4(dw[m][0], dw[m][1], dw[m][2], dw[m][3]);
            *(uint4*)&BuT[cb + (size_t)p * 64 + m * 16 + lk * 4] = vv;
        }
        const float4* lp = (const float4*)(lamP + 16 * p);
        float4 P0 = lp[0];
        float4 P1 = lp[1];
        float4 P2 = lp[2];
        float Lr = P0.x, Li = P0.y;
        float Fr[4], Fi[4];
        #pragma unroll
        for (int m = 0; m < 4; ++m) {
            float fr = 0.f, fi = 0.f;
            #pragma unroll
            for (int i = 0; i < 4; ++i) {
                float ur = __uint_as_float(dw[m][i] << 16);
                float ui = __uint_as_float(dw[m][i] & 0xffff0000u);
                float nr2 = Lr * fr - Li * fi + ur;
                float ni2 = Lr * fi + Li * fr + ui;
                fr = nr2; fi = ni2;
            }
            Fr[m] = fr; Fi[m] = fi;
        }
        float H0r = P2.x*Fr[0] - P2.y*Fi[0] + Fr[1];
        float H0i = P2.x*Fi[0] + P2.y*Fr[0] + Fi[1];
        float H1r = P2.x*Fr[2] - P2.y*Fi[2] + Fr[3];
        float H1i = P2.x*Fi[2] + P2.y*Fr[2] + Fi[3];
        float gr = (lk == 3) ? 1.f : (lk == 2) ? P0.z : (lk == 1) ? P1.x : P1.z;
        float gi = (lk == 3) ? 0.f : (lk == 2) ? P0.w : (lk == 1) ? P1.y : P1.w;
        float G0r = gr * H0r - gi * H0i, G0i = gr * H0i + gi * H0r;
        float G1r = gr * H1r - gi * H1i, G1i = gr * H1i + gi * H1r;
        G0r += __shfl_xor(G0r, 16); G0i += __shfl_xor(G0i, 16);
        G1r += __shfl_xor(G1r, 16); G1i += __shfl_xor(G1i, 16);
        G0r += __shfl_xor(G0r, 32); G0i += __shfl_xor(G0i, 32);
        G1r += __shfl_xor(G1r, 32); G1i += __shfl_xor(G1i, 32);
        if (evenl && lk == 0) {
            st[((size_t)ci * 2 + 0) * P_ + p] = make_float2(G0r, G0i);
            st[((size_t)ci * 2 + 1) * P_ + p] = make_float2(G1r, G1i);
        }
    }
}

__global__ __launch_bounds__(256) void s2_chain(
    const float* __restrict__ lamP, float2* __restrict__ st)
{
    int bl = blockIdx.x;
    int p = threadIdx.x;
    float ar = lamP[16 * p + 10], ai = lamP[16 * p + 11];
    float sr = 0.f, si = 0.f;
    float2* bp = st + (size_t)bl * NH * P_ + p;
    float2 f[8], fn[8];
    #pragma unroll
    for (int j = 0; j < 8; ++j) f[j] = bp[(size_t)j * P_];
    for (int c0 = 0; c0 < NH; c0 += 8) {
        if (c0 + 8 < NH) {
            #pragma unroll
            for (int j = 0; j < 8; ++j) fn[j] = bp[(size_t)(c0 + 8 + j) * P_];
        }
        #pragma unroll
        for (int j = 0; j < 8; ++j) {
            float2 t = f[j];
            bp[(size_t)(c0 + j) * P_] = make_float2(sr, si);
            float nr = ar * sr - ai * si + t.x;
            float ni = ar * si + ai * sr + t.y;
            sr = nr; si = ni;
        }
        #pragma unroll
        for (int j = 0; j < 8; ++j) f[j] = fn[j];
    }
}

__global__ __launch_bounds__(512, 4) void g2s_gemm(
    const unsigned* __restrict__ BuT,
    const unsigned short* __restrict__ Cf,
    const float* __restrict__ lam, const float2* __restrict__ st,
    const float* __restrict__ useg, const float* __restrict__ Dv,
    float* __restrict__ yseg)
{
    __shared__ __align__(16) char xs[65536];
    int tid = threadIdx.x, w = tid >> 6, lane = tid & 63;
    int ci = blockIdx.x;

    {
        int p = tid & 255, half = tid >> 8;
        float lr = lam[2 * p], li = lam[2 * p + 1];
        float2 s0 = st[((size_t)ci * 2 + half) * P_ + p];
        const uint4* bp = (const uint4*)(BuT + (size_t)ci * 16384 + (size_t)p * 64 + half * 32);
        uint4 dq[8];
        #pragma unroll
        for (int t = 0; t < 8; ++t) dq[t] = bp[t];
        float xr = s0.x, xi = s0.y;
        int T = p >> 5, qd = (p & 31) >> 2, pos = p & 3;
        char* base = xs + half * 32768 + T * 4096 + (pos << 2);
        #pragma unroll
        for (int t = 0; t < 8; ++t) {
            unsigned wv4[4] = {dq[t].x, dq[t].y, dq[t].z, dq[t].w};
            #pragma unroll
            for (int e = 0; e < 4; ++e) {
                int j = t * 4 + e;
                unsigned wv = wv4[e];
                float ur = __uint_as_float(wv << 16);
                float ui = __uint_as_float(wv & 0xffff0000u);
                float nr = lr * xr - li * xi + ur;
                float ni = lr * xi + li * xr + ui;
                xr = nr; xi = ni;
                *(unsigned*)(base + j * 128 + ((qd ^ (j & 7)) << 4)) = cvtpk(xr, xi);
            }
        }
    }

    int lr_ = lane & 15, lk = lane >> 4, r7 = lr_ & 7;
    int h0 = w * 32;
    const unsigned short* cf0 = Cf + (((size_t)(w * 2 + 0)) * 64 + lane) * 8;
    const unsigned short* cf1 = Cf + (((size_t)(w * 2 + 1)) * 64 + lane) * 8;

    f32x4 acc[4][2];
    #pragma unroll
    for (int m = 0; m < 4; ++m)
        #pragma unroll
        for (int n = 0; n < 2; ++n)
            acc[m][n] = (f32x4){0.f, 0.f, 0.f, 0.f};

    short8v bcur[2], bnxt[2];
    bcur[0] = *(const short8v*)cf0;
    bcur[1] = *(const short8v*)cf1;
    __syncthreads();

    #pragma unroll
    for (int kt = 0; kt < 16; ++kt) {
        if (kt < 15) {
            bnxt[0] = *(const short8v*)(cf0 + (size_t)(kt + 1) * 8192);
            bnxt[1] = *(const short8v*)(cf1 + (size_t)(kt + 1) * 8192);
        }
        int T = kt >> 1, q2 = (kt & 1) * 4 + lk;
        short8v a_[4];
        #pragma unroll
        for (int m = 0; m < 4; ++m)
            a_[m] = *(const short8v*)(xs + (m >> 1) * 32768 + T * 4096
                                      + ((m & 1) * 16 + lr_) * 128 + ((q2 ^ r7) << 4));
        #pragma unroll
        for (int m = 0; m < 4; ++m)
            acc[m][0] = __builtin_amdgcn_mfma_f32_16x16x32_bf16(a_[m], bcur[0], acc[m][0], 0, 0, 0);
        #pragma unroll
        for (int m = 0; m < 4; ++m)
            acc[m][1] = __builtin_amdgcn_mfma_f32_16x16x32_bf16(a_[m], bcur[1], acc[m][1], 0, 0, 0);
        bcur[0] = bnxt[0]; bcur[1] = bnxt[1];
    }

    float d_[2];
    #pragma unroll
    for (int n = 0; n < 2; ++n) d_[n] = Dv[h0 + n * 16 + lr_];
    #pragma unroll
    for (int m = 0; m < 4; ++m)
        #pragma unroll
        for (int n = 0; n < 2; ++n)
            #pragma unroll
            for (int i = 0; i < 4; ++i) {
                int rl = m * 16 + lk * 4 + i;
                int col = h0 + n * 16 + lr_;
                size_t off = ((size_t)ci * 64 + rl) * 256 + col;
                yseg[off] = acc[m][n][i] + d_[n] * useg[off];
            }
}

// ---------------- launch ----------------
extern "C" void kernel_launch(void* const* d_in, const int* in_sizes, int n_in,
                              void* d_out, int out_size, void* d_ws, size_t ws_size,
                              hipStream_t stream) {
    (void)in_sizes; (void)n_in; (void)out_size;
    const float* u    = (const float*)d_in[0];
    const float* Lre  = (const float*)d_in[1];
    const float* Lim  = (const float*)d_in[2];
    const float* Bre  = (const float*)d_in[3];
    const float* Bim  = (const float*)d_in[4];
    const float* Cre  = (const float*)d_in[5];
    const float* Cim  = (const float*)d_in[6];
    const float* Dv   = (const float*)d_in[7];
    const float* lstep= (const float*)d_in[8];

    char* w0 = (char*)d_ws;
    float* lam   = (float*)w0;  w0 += 2048;
    float* lamP  = (float*)w0;  w0 += (size_t)16 * P_ * 4;
    unsigned short* Bf = (unsigned short*)w0; w0 += (size_t)512 * 256 * 2;
    unsigned short* Cf = (unsigned short*)w0; w0 += (size_t)256 * 512 * 2;
    float2* stbuf = (float2*)w0; w0 += (size_t)16 * NH * P_ * 8;   // 4 MB
    unsigned* BuT = (unsigned*)w0;                                  // fallback

    k0_pre<<<256, 256, 0, stream>>>(Lre, Lim, Bre, Bim, Cre, Cim, lstep,
                                    lam, lamP, Bf, Cf);

    // capture-safe host-side guard: fused path needs 2 co-resident blocks/CU
    int occ = 0;
    hipError_t qe = hipOccupancyMaxActiveBlocksPerMultiprocessor(
        &occ, (const void*)fused_s5, 512, 0);
    bool use_fused = (qe == hipSuccess && occ >= 2);

    if (use_fused) {
        float* yout = (float*)d_out;
        void* args[] = {(void*)&u, (void*)&Bf, (void*)&Cf, (void*)&lam,
                        (void*)&lamP, (void*)&stbuf, (void*)&Dv, (void*)&yout};
        hipLaunchCooperativeKernel((void*)fused_s5, dim3(512), dim3(512),
                                   args, 0, stream);
    } else {
        // fallback: R12 pipeline, segments by workspace
        const size_t fixedsz = 2048 + (size_t)16 * P_ * 4
                             + (size_t)512 * 256 * 2 + (size_t)256 * 512 * 2
                             + (size_t)16 * NH * P_ * 8;
        const size_t perb = (size_t)L_ * 256 * 4;     // BuT per batch
        int nb = 4;
        if (ws_size >= fixedsz + 16 * perb + 4096) nb = 16;
        else if (ws_size >= fixedsz + 8 * perb + 4096) nb = 8;
        int nseg = B_ / nb;
        for (int s = 0; s < nseg; ++s) {
            const float* us = u + (size_t)s * nb * L_ * H_;
            float* ys = (float*)d_out + (size_t)s * nb * L_ * H_;
            g1c_gemm<<<dim3(nb * NC, 2), 512, 0, stream>>>(us, Bf, lamP, BuT, (float2*)stbuf);
            s2_chain<<<nb, 256, 0, stream>>>(lamP, (float2*)stbuf);
            g2s_gemm<<<nb * NC, 512, 0, stream>>>(BuT, Cf, lam, (float2*)stbuf, us, Dv, ys);
        }
    }
}